// Round 9
// baseline (453.953 us; speedup 1.0000x reference)
//
#include <hip/hip_runtime.h>

// Fused attention block (b=2, n=2048, dim=256, heads=8, inner=16384, d_head=2048)
// LOW-RANK: S_h = xn M_h xn^T (M_h = Wq_h^T Wk_h), Zt_h = N_h xn^T (N_h = Wo_h Wv_h).
// FLASH-FUSED core, R9: register-resident operands, (almost) barrier-free.
//   - Y i-tile A-fragments preloaded to registers (loop-invariant across jt)
//   - xn / Zt B-fragments loaded straight from global (L2-resident) in MFMA layout
//   - LDS only for P C->A layout transform: 2 barriers/jt (was 24)
// Per block (i-tile 64, h, b): 16 j-tiles: S=Y.xn^T (K=256) -> exp (+l partials)
// -> Pl -> PV acc_o += P.Zt^T (K=128).  End: reduce l, scale 1/l, fp32 atomics.
// Pre-GEMMs unchanged (m97-recipe gemm_bt): Mt/N split-K, Y = xn Mt^T, Zt = N xn^T.

typedef unsigned short u16;
typedef unsigned int u32;
typedef __bf16 bf16x8 __attribute__((ext_vector_type(8)));
typedef float f32x4 __attribute__((ext_vector_type(4)));

__device__ __forceinline__ u16 f2bf(float f) {
    u32 u = __builtin_bit_cast(u32, f);
    u += 0x7fffu + ((u >> 16) & 1u);   // RNE; inputs finite
    return (u16)(u >> 16);
}

#define GLDS16(G, L)                                                                  \
    __builtin_amdgcn_global_load_lds((const __attribute__((address_space(1))) u32*)(G), \
                                     (__attribute__((address_space(3))) u32*)(L), 16, 0, 0)

// ---------------------------------------------------------------------------
// B^T GEMM: C[m,n] (+)= sum_k A[m,k]*B[n,k].  blockIdx.z = (kc*NB+zb)*H + zh.
// ---------------------------------------------------------------------------
template <typename OutT, bool ATOMIC>
__global__ void __launch_bounds__(256, 4) gemm_bt(
    const u16* __restrict__ A, const u16* __restrict__ B, OutT* __restrict__ C,
    int K, int lda, int ldb, int ldc,
    long sAh, long sAb, long sBh, long sBb, long sCh, long sCb,
    int H, int NB, long ksA, long ksB)
{
    __shared__ u16 ldsA[128 * 32];
    __shared__ u16 ldsB[128 * 32];

    const int z = blockIdx.z;
    const int zh = z % H;
    const int zq = z / H;
    const int zb = zq % NB;
    const int kc = zq / NB;
    A += (size_t)zh * sAh + (size_t)zb * sAb + (size_t)kc * ksA;
    B += (size_t)zh * sBh + (size_t)zb * sBb + (size_t)kc * ksB;
    C += (size_t)zh * sCh + (size_t)zb * sCb;

    const int bm = blockIdx.y * 128;
    const int bn = blockIdx.x * 128;
    const int t = threadIdx.x;
    const int w = t >> 6, l = t & 63;
    const int wm = w >> 1, wn = w & 1;
    const int lr = l & 15, lk = l >> 4;
    const int sw = lk ^ ((lr >> 1) & 3);

    const int m0 = t >> 2, s0 = t & 3;
    const int c0 = s0 ^ ((m0 >> 1) & 3);
    const int m1 = 64 + m0;
    const int c1 = s0 ^ ((m1 >> 1) & 3);

    const u16* gA0 = A + (size_t)(bm + m0) * lda + c0 * 8;
    const u16* gA1 = A + (size_t)(bm + m1) * lda + c1 * 8;
    const u16* gB0 = B + (size_t)(bn + m0) * ldb + c0 * 8;
    const u16* gB1 = B + (size_t)(bn + m1) * ldb + c1 * 8;
    u16* lA0 = &ldsA[(t & ~63) * 8];
    u16* lA1 = &ldsA[(256 + (t & ~63)) * 8];
    u16* lB0 = &ldsB[(t & ~63) * 8];
    u16* lB1 = &ldsB[(256 + (t & ~63)) * 8];

    f32x4 acc[4][4];
#pragma unroll
    for (int i = 0; i < 4; ++i)
#pragma unroll
        for (int j = 0; j < 4; ++j)
            acc[i][j] = f32x4{0.f, 0.f, 0.f, 0.f};

    const int nk = K >> 5;
    for (int kt = 0; kt < nk; ++kt) {
        __syncthreads();
        GLDS16(gA0, lA0); GLDS16(gA1, lA1);
        GLDS16(gB0, lB0); GLDS16(gB1, lB1);
        gA0 += 32; gA1 += 32; gB0 += 32; gB1 += 32;
        __syncthreads();

        bf16x8 av[4], bv[4];
#pragma unroll
        for (int i = 0; i < 4; ++i) {
            av[i] = *(const bf16x8*)&ldsA[(wm * 64 + i * 16 + lr) * 32 + sw * 8];
            bv[i] = *(const bf16x8*)&ldsB[(wn * 64 + i * 16 + lr) * 32 + sw * 8];
        }
#pragma unroll
        for (int i = 0; i < 4; ++i)
#pragma unroll
            for (int j = 0; j < 4; ++j)
                acc[i][j] = __builtin_amdgcn_mfma_f32_16x16x32_bf16(av[i], bv[j], acc[i][j], 0, 0, 0);
    }

    // C/D layout: col = lane&15, row = (lane>>4)*4 + reg
#pragma unroll
    for (int i = 0; i < 4; ++i) {
        const int row0 = bm + wm * 64 + i * 16 + lk * 4;
#pragma unroll
        for (int j = 0; j < 4; ++j) {
            const int col = bn + wn * 64 + j * 16 + lr;
#pragma unroll
            for (int r = 0; r < 4; ++r) {
                const size_t idx = (size_t)(row0 + r) * ldc + col;
                const float v = acc[i][j][r];
                if constexpr (ATOMIC) {
                    atomicAdd(&C[idx], v);
                } else if constexpr (sizeof(OutT) == 2) {
                    C[idx] = (OutT)f2bf(v);
                } else {
                    C[idx] = (OutT)v;
                }
            }
        }
    }
}

// ---------------------------------------------------------------------------
// Flash-fused attention core, register/L2-fed.  Grid (32 i-tiles, 16 hb), 256 thr.
// Y  : [4096][2048]  row b*2048+i, col h*256+a  (SCALE folded)
// xn : [4096][256]
// Zt : [2][2048][2048] row h*256+d', col j
// out: [4096][256] fp32, atomic (sum over heads)
// ---------------------------------------------------------------------------
__global__ void __launch_bounds__(256, 2) attn_fused(
    const u16* __restrict__ Y, const u16* __restrict__ xn,
    const u16* __restrict__ Zt, float* __restrict__ out)
{
    __shared__ u16 Pl[64 * 136];       // P tile (64x128, stride 136 = 16B-aligned rows)
    __shared__ float l_lds[64];

    const int i0 = blockIdx.x * 64;
    const int hb = blockIdx.y;
    const int h = hb >> 1, b = hb & 1;

    const int t = threadIdx.x;
    const int w = t >> 6, l = t & 63;
    const int wm = w >> 1, wn = w & 1;          // wm: 32-row half; wn: col half
    const int lr = l & 15, lk = l >> 4;

    if (t < 64) l_lds[t] = 0.f;

    const u16* xb = xn + (size_t)b * 2048 * 256;
    const u16* Zb = Zt + (size_t)b * 4194304 + (size_t)h * 524288;

    // ---- preload Y A-fragments (loop-invariant): rows wm*32+i*16+lr, k = kt*32+lk*8
    bf16x8 av_y[2][8];
#pragma unroll
    for (int i = 0; i < 2; ++i)
#pragma unroll
        for (int kt = 0; kt < 8; ++kt)
            av_y[i][kt] = *(const bf16x8*)(Y + (size_t)(b * 2048 + i0 + wm * 32 + i * 16 + lr) * 2048
                                             + h * 256 + kt * 32 + lk * 8);

    f32x4 acc_o[2][8];
#pragma unroll
    for (int i = 0; i < 2; ++i)
#pragma unroll
        for (int j = 0; j < 8; ++j)
            acc_o[i][j] = f32x4{0.f, 0.f, 0.f, 0.f};
    float lsum[8];
#pragma unroll
    for (int i = 0; i < 8; ++i) lsum[i] = 0.f;

    for (int jt = 0; jt < 16; ++jt) {
        const int j0 = jt * 128;

        // ---- S phase: acc_s = Y_h[i-tile] . xn[j-tile]^T, K=256, no LDS/barriers
        f32x4 acc_s[2][4];
#pragma unroll
        for (int i = 0; i < 2; ++i)
#pragma unroll
            for (int j = 0; j < 4; ++j)
                acc_s[i][j] = f32x4{0.f, 0.f, 0.f, 0.f};

#pragma unroll
        for (int kt = 0; kt < 8; ++kt) {
            bf16x8 bv[4];
#pragma unroll
            for (int j = 0; j < 4; ++j)
                bv[j] = *(const bf16x8*)(xb + (size_t)(j0 + wn * 64 + j * 16 + lr) * 256
                                            + kt * 32 + lk * 8);
#pragma unroll
            for (int i = 0; i < 2; ++i)
#pragma unroll
                for (int j = 0; j < 4; ++j)
                    acc_s[i][j] = __builtin_amdgcn_mfma_f32_16x16x32_bf16(av_y[i][kt], bv[j], acc_s[i][j], 0, 0, 0);
        }

        // ---- exp + l partials + P -> LDS (C-layout -> [row][col]) ----
#pragma unroll
        for (int i = 0; i < 2; ++i)
#pragma unroll
            for (int j = 0; j < 4; ++j)
#pragma unroll
                for (int r = 0; r < 4; ++r) {
                    const float e = __expf(acc_s[i][j][r]);
                    lsum[i * 4 + r] += e;
                    Pl[(wm * 32 + i * 16 + lk * 4 + r) * 136 + wn * 64 + j * 16 + lr] = f2bf(e);
                }
        __syncthreads();                        // P visible to all waves

        // ---- PV phase: acc_o += P . Zt-tile^T, K=128, B from global ----
#pragma unroll
        for (int kt = 0; kt < 4; ++kt) {
            bf16x8 av[2];
#pragma unroll
            for (int i = 0; i < 2; ++i)
                av[i] = *(const bf16x8*)&Pl[(wm * 32 + i * 16 + lr) * 136 + kt * 32 + lk * 8];
#pragma unroll
            for (int jf = 0; jf < 8; ++jf) {
                const bf16x8 bz = *(const bf16x8*)(Zb + (size_t)(wn * 128 + jf * 16 + lr) * 2048
                                                      + j0 + kt * 32 + lk * 8);
#pragma unroll
                for (int i = 0; i < 2; ++i)
                    acc_o[i][jf] = __builtin_amdgcn_mfma_f32_16x16x32_bf16(av[i], bz, acc_o[i][jf], 0, 0, 0);
            }
        }
        __syncthreads();                        // Pl reusable next jt
    }

    // ---- finalize l: butterfly over 16 lr lanes, cross-wave LDS atomic ----
#pragma unroll
    for (int i = 0; i < 2; ++i)
#pragma unroll
        for (int r = 0; r < 4; ++r) {
            float s = lsum[i * 4 + r];
            s += __shfl_xor(s, 1, 64);
            s += __shfl_xor(s, 2, 64);
            s += __shfl_xor(s, 4, 64);
            s += __shfl_xor(s, 8, 64);
            if (lr == 0) atomicAdd(&l_lds[wm * 32 + i * 16 + lk * 4 + r], s);
        }
    __syncthreads();

    // ---- scale by 1/l, atomic-accumulate into out (sum over heads) ----
#pragma unroll
    for (int i = 0; i < 2; ++i)
#pragma unroll
        for (int r = 0; r < 4; ++r) {
            const int row = wm * 32 + i * 16 + lk * 4 + r;
            const float rl = 1.0f / l_lds[row];
            float* orow = out + (size_t)(b * 2048 + i0 + row) * 256 + wn * 128;
#pragma unroll
            for (int jf = 0; jf < 8; ++jf)
                atomicAdd(&orow[jf * 16 + lr], acc_o[i][jf][r] * rl);
        }
}

// ---------------------------------------------------------------------------
// Transposed cast: src fp32 [8][2048][256] -> dst bf16 [8][256][2048].
// ---------------------------------------------------------------------------
__global__ void __launch_bounds__(256) tcast_kernel(const float* __restrict__ src,
                                                    u16* __restrict__ dst, float scale)
{
    __shared__ u16 tile[64][66];
    const int h = blockIdx.z;
    const int d0 = blockIdx.x * 64;
    const int a0 = blockIdx.y * 64;
    const int t = threadIdx.x;
    const int c = t & 63, r0 = t >> 6;
#pragma unroll
    for (int rr = 0; rr < 16; ++rr) {
        const int r = r0 + rr * 4;
        tile[r][c] = f2bf(src[((size_t)h * 2048 + d0 + r) * 256 + a0 + c] * scale);
    }
    __syncthreads();
#pragma unroll
    for (int rr = 0; rr < 16; ++rr) {
        const int r = r0 + rr * 4;
        dst[((size_t)h * 256 + a0 + r) * 2048 + d0 + c] = tile[c][r];
    }
}

__global__ void __launch_bounds__(64) ln_kernel(const float* __restrict__ x,
                                                const float* __restrict__ g,
                                                u16* __restrict__ xn)
{
    const size_t row = blockIdx.x;
    const int l = threadIdx.x;
    const float4 v = ((const float4*)(x + row * 256))[l];
    float s = v.x + v.y + v.z + v.w;
    float q = v.x * v.x + v.y * v.y + v.z * v.z + v.w * v.w;
#pragma unroll
    for (int o = 32; o > 0; o >>= 1) {
        s += __shfl_xor(s, o, 64);
        q += __shfl_xor(q, o, 64);
    }
    const float mu = s * (1.0f / 256.0f);
    const float var = q * (1.0f / 256.0f) - mu * mu;
    const float rs = rsqrtf(var + 1e-5f);
    const float4 gg = ((const float4*)g)[l];
    ushort4 o4;
    o4.x = f2bf((v.x - mu) * rs * (gg.x + 1.0f));
    o4.y = f2bf((v.y - mu) * rs * (gg.y + 1.0f));
    o4.z = f2bf((v.z - mu) * rs * (gg.z + 1.0f));
    o4.w = f2bf((v.w - mu) * rs * (gg.w + 1.0f));
    ((ushort4*)(xn + row * 256))[l] = o4;
}

__global__ void __launch_bounds__(256) cast_bf16_kernel(const float* __restrict__ src,
                                                        u16* __restrict__ dst, float scale)
{
    const size_t i = (size_t)blockIdx.x * 256 + threadIdx.x;
    const float4 v = ((const float4*)src)[i];
    ushort4 o4;
    o4.x = f2bf(v.x * scale);
    o4.y = f2bf(v.y * scale);
    o4.z = f2bf(v.z * scale);
    o4.w = f2bf(v.w * scale);
    ((ushort4*)dst)[i] = o4;
}

extern "C" void kernel_launch(void* const* d_in, const int* in_sizes, int n_in,
                              void* d_out, int out_size, void* d_ws, size_t ws_size,
                              hipStream_t stream)
{
    (void)in_sizes; (void)n_in; (void)ws_size;
    const float* x     = (const float*)d_in[0];
    const float* gamma = (const float*)d_in[1];
    const float* Wq    = (const float*)d_in[2];
    const float* Wk    = (const float*)d_in[3];
    const float* Wv    = (const float*)d_in[4];
    const float* Wo    = (const float*)d_in[5];
    float* out = (float*)d_out;

    char* ws = (char*)d_ws;
    const size_t MB = 1048576;
    u16* wqt   = (u16*)(ws);             // [8][256][2048] bf16 (SCALE folded)
    u16* wkt   = (u16*)(ws + 8 * MB);
    u16* wvt   = (u16*)(ws + 16 * MB);
    u16* wo    = (u16*)(ws + 24 * MB);   // [256][16384] bf16
    u16* xn    = (u16*)(ws + 32 * MB);   // [4096][256] bf16
    u16* Mt    = (u16*)(ws + 34 * MB);   // [8*256][256] bf16 (Mt_h = M_h^T)
    u16* Nb    = (u16*)(ws + 35 * MB);   // [8*256][256] bf16
    float* MtF = (float*)(ws + 36 * MB); // fp32 split-K accum for Mt (2 MB)
    float* NbF = (float*)(ws + 40 * MB); // fp32 split-K accum for Nb (2 MB)
    u16* Y     = (u16*)(ws + 44 * MB);   // [4096][2048] bf16
    u16* Zt    = (u16*)(ws + 60 * MB);   // [2][2048][2048] bf16

    hipMemsetAsync(d_out, 0, (size_t)out_size * sizeof(float), stream);
    hipMemsetAsync(MtF, 0, 2 * MB, stream);
    hipMemsetAsync(NbF, 0, 2 * MB, stream);

    tcast_kernel<<<dim3(32, 4, 8), 256, 0, stream>>>(Wq, wqt, 0.125f);
    tcast_kernel<<<dim3(32, 4, 8), 256, 0, stream>>>(Wk, wkt, 1.0f);
    tcast_kernel<<<dim3(32, 4, 8), 256, 0, stream>>>(Wv, wvt, 1.0f);
    cast_bf16_kernel<<<4096, 256, 0, stream>>>(Wo, wo, 1.0f);
    ln_kernel<<<4096, 64, 0, stream>>>(x, gamma, xn);

    // Mt_h[a,c] = sum_e wkt_h[a,e]*wqt_h[c,e] : split-K x4 (K-chunk 512), fp32 atomic
    gemm_bt<float, true><<<dim3(2, 2, 32), 256, 0, stream>>>(
        wkt, wqt, MtF, 512, 2048, 2048, 256,
        524288L, 0, 524288L, 0, 65536L, 0, 8, 1, 512L, 512L);

    // N_h[d',a] = sum_e Wo[d',h*2048+e]*wvt_h[a,e] : split-K x4, fp32 atomic
    gemm_bt<float, true><<<dim3(2, 2, 32), 256, 0, stream>>>(
        wo, wvt, NbF, 512, 16384, 2048, 256,
        2048L, 0, 524288L, 0, 65536L, 0, 8, 1, 512L, 512L);

    cast_bf16_kernel<<<512, 256, 0, stream>>>(MtF, Mt, 1.0f);
    cast_bf16_kernel<<<512, 256, 0, stream>>>(NbF, Nb, 1.0f);

    // Y[t, h*256+a] = sum_c xn[t,c] * Mt[h*256+a, c]
    gemm_bt<u16, false><<<dim3(16, 32, 1), 256, 0, stream>>>(
        xn, Mt, Y, 256, 256, 256, 2048,
        0, 0, 0, 0, 0, 0, 1, 1, 0, 0);

    // Zt[b][h*256+d', j] = sum_a Nb[h*256+d', a] * xn[b*2048+j, a]
    gemm_bt<u16, false><<<dim3(16, 16, 2), 256, 0, stream>>>(
        Nb, xn, Zt, 256, 256, 256, 2048,
        0, 0, 0, 524288L, 0, 4194304L, 1, 2, 0, 0);

    // fused S -> softmax -> PV -> head-sum
    attn_fused<<<dim3(32, 16), 256, 0, stream>>>(Y, xn, Zt, out);
}

// Round 10
// 300.441 us; speedup vs baseline: 1.5110x; 1.5110x over previous
//
#include <hip/hip_runtime.h>

// Fused attention block (b=2, n=2048, dim=256, heads=8, inner=16384, d_head=2048)
// LOW-RANK: S_h = xn M_h xn^T (M_h = Wq_h^T Wk_h), Zt_h = N_h xn^T (N_h = Wo_h Wv_h).
// FLASH core R10: ALL fragment operands via coalesced global_load_lds staging
// (R9's direct-global scatter was latency death); Y i-tile staged ONCE; 2 blocks/CU
// (R8 ran 1 block/CU and was barrier-drain-bound).  Per block (i-tile 64, h, b):
// 16 j-tiles: S = Y.xn^T (K=256, BK=32) -> exp (+l partials) -> Pl (C->A layout)
// -> PV acc_o += P.Zt^T (K=128, BK=32).  End: reduce l, scale 1/l, fp32 atomics.
// Pre-GEMMs (m97 recipe): Mt/N split-K, Y = xn Mt^T, Zt = N xn^T.

typedef unsigned short u16;
typedef unsigned int u32;
typedef __bf16 bf16x8 __attribute__((ext_vector_type(8)));
typedef float f32x4 __attribute__((ext_vector_type(4)));

__device__ __forceinline__ u16 f2bf(float f) {
    u32 u = __builtin_bit_cast(u32, f);
    u += 0x7fffu + ((u >> 16) & 1u);   // RNE; inputs finite
    return (u16)(u >> 16);
}

#define GLDS16(G, L)                                                                  \
    __builtin_amdgcn_global_load_lds((const __attribute__((address_space(1))) u32*)(G), \
                                     (__attribute__((address_space(3))) u32*)(L), 16, 0, 0)

// ---------------------------------------------------------------------------
// B^T GEMM: C[m,n] (+)= sum_k A[m,k]*B[n,k].  blockIdx.z = (kc*NB+zb)*H + zh.
// ---------------------------------------------------------------------------
template <typename OutT, bool ATOMIC>
__global__ void __launch_bounds__(256, 4) gemm_bt(
    const u16* __restrict__ A, const u16* __restrict__ B, OutT* __restrict__ C,
    int K, int lda, int ldb, int ldc,
    long sAh, long sAb, long sBh, long sBb, long sCh, long sCb,
    int H, int NB, long ksA, long ksB)
{
    __shared__ u16 ldsA[128 * 32];
    __shared__ u16 ldsB[128 * 32];

    const int z = blockIdx.z;
    const int zh = z % H;
    const int zq = z / H;
    const int zb = zq % NB;
    const int kc = zq / NB;
    A += (size_t)zh * sAh + (size_t)zb * sAb + (size_t)kc * ksA;
    B += (size_t)zh * sBh + (size_t)zb * sBb + (size_t)kc * ksB;
    C += (size_t)zh * sCh + (size_t)zb * sCb;

    const int bm = blockIdx.y * 128;
    const int bn = blockIdx.x * 128;
    const int t = threadIdx.x;
    const int w = t >> 6, l = t & 63;
    const int wm = w >> 1, wn = w & 1;
    const int lr = l & 15, lk = l >> 4;
    const int sw = lk ^ ((lr >> 1) & 3);

    const int m0 = t >> 2, s0 = t & 3;
    const int c0 = s0 ^ ((m0 >> 1) & 3);
    const int m1 = 64 + m0;
    const int c1 = s0 ^ ((m1 >> 1) & 3);

    const u16* gA0 = A + (size_t)(bm + m0) * lda + c0 * 8;
    const u16* gA1 = A + (size_t)(bm + m1) * lda + c1 * 8;
    const u16* gB0 = B + (size_t)(bn + m0) * ldb + c0 * 8;
    const u16* gB1 = B + (size_t)(bn + m1) * ldb + c1 * 8;
    u16* lA0 = &ldsA[(t & ~63) * 8];
    u16* lA1 = &ldsA[(256 + (t & ~63)) * 8];
    u16* lB0 = &ldsB[(t & ~63) * 8];
    u16* lB1 = &ldsB[(256 + (t & ~63)) * 8];

    f32x4 acc[4][4];
#pragma unroll
    for (int i = 0; i < 4; ++i)
#pragma unroll
        for (int j = 0; j < 4; ++j)
            acc[i][j] = f32x4{0.f, 0.f, 0.f, 0.f};

    const int nk = K >> 5;
    for (int kt = 0; kt < nk; ++kt) {
        __syncthreads();
        GLDS16(gA0, lA0); GLDS16(gA1, lA1);
        GLDS16(gB0, lB0); GLDS16(gB1, lB1);
        gA0 += 32; gA1 += 32; gB0 += 32; gB1 += 32;
        __syncthreads();

        bf16x8 av[4], bv[4];
#pragma unroll
        for (int i = 0; i < 4; ++i) {
            av[i] = *(const bf16x8*)&ldsA[(wm * 64 + i * 16 + lr) * 32 + sw * 8];
            bv[i] = *(const bf16x8*)&ldsB[(wn * 64 + i * 16 + lr) * 32 + sw * 8];
        }
#pragma unroll
        for (int i = 0; i < 4; ++i)
#pragma unroll
            for (int j = 0; j < 4; ++j)
                acc[i][j] = __builtin_amdgcn_mfma_f32_16x16x32_bf16(av[i], bv[j], acc[i][j], 0, 0, 0);
    }

    // C/D layout: col = lane&15, row = (lane>>4)*4 + reg
#pragma unroll
    for (int i = 0; i < 4; ++i) {
        const int row0 = bm + wm * 64 + i * 16 + lk * 4;
#pragma unroll
        for (int j = 0; j < 4; ++j) {
            const int col = bn + wn * 64 + j * 16 + lr;
#pragma unroll
            for (int r = 0; r < 4; ++r) {
                const size_t idx = (size_t)(row0 + r) * ldc + col;
                const float v = acc[i][j][r];
                if constexpr (ATOMIC) {
                    atomicAdd(&C[idx], v);
                } else if constexpr (sizeof(OutT) == 2) {
                    C[idx] = (OutT)f2bf(v);
                } else {
                    C[idx] = (OutT)v;
                }
            }
        }
    }
}

// ---------------------------------------------------------------------------
// Flash-fused attention core.  Grid (32 i-tiles, 16 hb).  256 thr, 2 blocks/CU.
// Y  : [4096][2048]  row b*2048+i, col h*256+a  (SCALE folded)
// xn : [4096][256]
// Zt : [2][2048][2048] row h*256+d', col j
// out: [4096][256] fp32, atomic (sum over heads)
// ---------------------------------------------------------------------------
__global__ void __launch_bounds__(256, 2) attn_fused(
    const u16* __restrict__ Y, const u16* __restrict__ xn,
    const u16* __restrict__ Zt, float* __restrict__ out)
{
    __shared__ u16 ldsY[8 * 64 * 32];  // 32 KB: Y i-tile, 8 k-subtiles [64][32]
    __shared__ u16 ldsB[128 * 32];     // 8 KB: xn j-subtile
    __shared__ u16 ldsZ[256 * 32];     // 16 KB: Zt subtile
    __shared__ u16 Pl[64 * 136];       // 17 KB: P tile (pad 136: 16B-aligned, 2-way free)
    __shared__ float l_lds[64];

    const int i0 = blockIdx.x * 64;
    const int hb = blockIdx.y;
    const int h = hb >> 1, b = hb & 1;

    const int t = threadIdx.x;
    const int w = t >> 6, l = t & 63;
    const int wm = w >> 1, wn = w & 1;
    const int lr = l & 15, lk = l >> 4;
    const int sw = lk ^ ((lr >> 1) & 3);

    if (t < 64) l_lds[t] = 0.f;

    const u16* Yb = Y + (size_t)(b * 2048 + i0) * 2048 + h * 256;
    const u16* xb = xn + (size_t)b * 2048 * 256;
    const u16* Zb = Zt + (size_t)b * 4194304 + (size_t)h * 524288;

    // ---- prologue: stage Y i-tile (64 rows x 256 k) once, gemm_bt swizzle per
    // 4KB subtile: chunk q = p*256 + t; kt=q>>8, qq=q&255, m=qq>>2, s=qq&3,
    // global chunk c = s ^ ((m>>1)&3); LDS dest sequential (wave-uniform + lane*16).
#pragma unroll
    for (int p = 0; p < 8; ++p) {
        const int q = p * 256 + t;
        const int kt = q >> 8, qq = q & 255;
        const int m = qq >> 2, s = qq & 3;
        const int c = s ^ ((m >> 1) & 3);
        GLDS16(Yb + (size_t)m * 2048 + kt * 32 + c * 8,
               &ldsY[(p * 256 + (t & ~63)) * 8]);
    }

    // staging roles for xn (2 chunks/thread) and Zt (4 chunks/thread)
    const int m0 = t >> 2, s0 = t & 3;
    const int c0 = s0 ^ ((m0 >> 1) & 3);
    const int m1 = 64 + m0;
    const int c1 = s0 ^ ((m1 >> 1) & 3);
    u16* lB0 = &ldsB[(t & ~63) * 8];
    u16* lB1 = &ldsB[(256 + (t & ~63)) * 8];

    const u16 *gZ0, *gZ1, *gZ2, *gZ3;
    u16 *lZ0, *lZ1, *lZ2, *lZ3;
    {
        const int q0 = t, q1 = 256 + t, q2 = 512 + t, q3 = 768 + t;
        const int mz0 = q0 >> 2, mz1 = q1 >> 2, mz2 = q2 >> 2, mz3 = q3 >> 2;
        const int cz0 = (q0 & 3) ^ ((mz0 >> 1) & 3);
        const int cz1 = (q1 & 3) ^ ((mz1 >> 1) & 3);
        const int cz2 = (q2 & 3) ^ ((mz2 >> 1) & 3);
        const int cz3 = (q3 & 3) ^ ((mz3 >> 1) & 3);
        gZ0 = Zb + (size_t)mz0 * 2048 + cz0 * 8;
        gZ1 = Zb + (size_t)mz1 * 2048 + cz1 * 8;
        gZ2 = Zb + (size_t)mz2 * 2048 + cz2 * 8;
        gZ3 = Zb + (size_t)mz3 * 2048 + cz3 * 8;
        lZ0 = &ldsZ[(t & ~63) * 8];
        lZ1 = &ldsZ[(256 + (t & ~63)) * 8];
        lZ2 = &ldsZ[(512 + (t & ~63)) * 8];
        lZ3 = &ldsZ[(768 + (t & ~63)) * 8];
    }

    f32x4 acc_o[2][8];
#pragma unroll
    for (int i = 0; i < 2; ++i)
#pragma unroll
        for (int j = 0; j < 8; ++j)
            acc_o[i][j] = f32x4{0.f, 0.f, 0.f, 0.f};
    float lsum[8];
#pragma unroll
    for (int i = 0; i < 8; ++i) lsum[i] = 0.f;

    __syncthreads();                   // Y tile staged (drains prologue vmcnt)

    for (int jt = 0; jt < 16; ++jt) {
        const int j0 = jt * 128;

        // ---- S phase: acc_s = Y[i-tile] . xn[j-tile]^T, K=256, BK=32 ----
        f32x4 acc_s[2][4];
#pragma unroll
        for (int i = 0; i < 2; ++i)
#pragma unroll
            for (int j = 0; j < 4; ++j)
                acc_s[i][j] = f32x4{0.f, 0.f, 0.f, 0.f};

#pragma unroll
        for (int kt = 0; kt < 8; ++kt) {
            __syncthreads();           // ldsB safe to overwrite
            GLDS16(xb + (size_t)(j0 + m0) * 256 + kt * 32 + c0 * 8, lB0);
            GLDS16(xb + (size_t)(j0 + m1) * 256 + kt * 32 + c1 * 8, lB1);
            __syncthreads();           // tile staged
            bf16x8 av[2], bv[4];
#pragma unroll
            for (int i = 0; i < 2; ++i)
                av[i] = *(const bf16x8*)&ldsY[kt * 2048 + (wm * 32 + i * 16 + lr) * 32 + sw * 8];
#pragma unroll
            for (int j = 0; j < 4; ++j)
                bv[j] = *(const bf16x8*)&ldsB[(wn * 64 + j * 16 + lr) * 32 + sw * 8];
#pragma unroll
            for (int i = 0; i < 2; ++i)
#pragma unroll
                for (int j = 0; j < 4; ++j)
                    acc_s[i][j] = __builtin_amdgcn_mfma_f32_16x16x32_bf16(av[i], bv[j], acc_s[i][j], 0, 0, 0);
        }

        // ---- exp + l partials + P -> LDS (C-layout -> [row][col]) ----
#pragma unroll
        for (int i = 0; i < 2; ++i)
#pragma unroll
            for (int j = 0; j < 4; ++j)
#pragma unroll
                for (int r = 0; r < 4; ++r) {
                    const float e = __expf(acc_s[i][j][r]);
                    lsum[i * 4 + r] += e;
                    Pl[(wm * 32 + i * 16 + lk * 4 + r) * 136 + wn * 64 + j * 16 + lr] = f2bf(e);
                }
        __syncthreads();               // P visible to all waves

        // ---- PV phase: acc_o += P . Zt-tile^T, K=128, BK=32 ----
#pragma unroll
        for (int kt = 0; kt < 4; ++kt) {
            GLDS16(gZ0 + j0 + kt * 32, lZ0);
            GLDS16(gZ1 + j0 + kt * 32, lZ1);
            GLDS16(gZ2 + j0 + kt * 32, lZ2);
            GLDS16(gZ3 + j0 + kt * 32, lZ3);
            __syncthreads();           // tile staged
            bf16x8 av[2];
#pragma unroll
            for (int i = 0; i < 2; ++i)
                av[i] = *(const bf16x8*)&Pl[(wm * 32 + i * 16 + lr) * 136 + kt * 32 + lk * 8];
#pragma unroll
            for (int jf = 0; jf < 8; ++jf) {
                const bf16x8 bz = *(const bf16x8*)&ldsZ[(wn * 128 + jf * 16 + lr) * 32 + sw * 8];
#pragma unroll
                for (int i = 0; i < 2; ++i)
                    acc_o[i][jf] = __builtin_amdgcn_mfma_f32_16x16x32_bf16(av[i], bz, acc_o[i][jf], 0, 0, 0);
            }
            __syncthreads();           // ldsZ safe to overwrite (Pl reads done this kt)
        }
    }

    // ---- finalize l: butterfly over lr lanes, cross-wave LDS atomic ----
#pragma unroll
    for (int i = 0; i < 2; ++i)
#pragma unroll
        for (int r = 0; r < 4; ++r) {
            float s = lsum[i * 4 + r];
            s += __shfl_xor(s, 1, 64);
            s += __shfl_xor(s, 2, 64);
            s += __shfl_xor(s, 4, 64);
            s += __shfl_xor(s, 8, 64);
            if (lr == 0) atomicAdd(&l_lds[wm * 32 + i * 16 + lk * 4 + r], s);
        }
    __syncthreads();

    // ---- scale by 1/l, atomic-accumulate into out (sum over heads) ----
#pragma unroll
    for (int i = 0; i < 2; ++i)
#pragma unroll
        for (int r = 0; r < 4; ++r) {
            const int row = wm * 32 + i * 16 + lk * 4 + r;
            const float rl = 1.0f / l_lds[row];
            float* orow = out + (size_t)(b * 2048 + i0 + row) * 256 + wn * 128;
#pragma unroll
            for (int jf = 0; jf < 8; ++jf)
                atomicAdd(&orow[jf * 16 + lr], acc_o[i][jf][r] * rl);
        }
}

// ---------------------------------------------------------------------------
// Transposed cast for Wq/Wk/Wv in one dispatch: z = wsel*8 + h.
// src fp32 [8][2048][256] -> dst bf16 [8][256][2048] (contiguous 3 weights).
// ---------------------------------------------------------------------------
__global__ void __launch_bounds__(256) tcast3_kernel(const float* __restrict__ Wq,
                                                     const float* __restrict__ Wk,
                                                     const float* __restrict__ Wv,
                                                     u16* __restrict__ dst)
{
    __shared__ u16 tile[64][66];
    const int z = blockIdx.z;
    const int wsel = z >> 3, h = z & 7;
    const float* src = (wsel == 0) ? Wq : (wsel == 1) ? Wk : Wv;
    const float scale = (wsel == 0) ? 0.125f : 1.0f;
    u16* d = dst + (size_t)wsel * 4194304;
    const int d0 = blockIdx.x * 64;
    const int a0 = blockIdx.y * 64;
    const int t = threadIdx.x;
    const int c = t & 63, r0 = t >> 6;
#pragma unroll
    for (int rr = 0; rr < 16; ++rr) {
        const int r = r0 + rr * 4;
        tile[r][c] = f2bf(src[((size_t)h * 2048 + d0 + r) * 256 + a0 + c] * scale);
    }
    __syncthreads();
#pragma unroll
    for (int rr = 0; rr < 16; ++rr) {
        const int r = r0 + rr * 4;
        d[((size_t)h * 256 + a0 + r) * 2048 + d0 + c] = tile[c][r];
    }
}

__global__ void __launch_bounds__(64) ln_kernel(const float* __restrict__ x,
                                                const float* __restrict__ g,
                                                u16* __restrict__ xn)
{
    const size_t row = blockIdx.x;
    const int l = threadIdx.x;
    const float4 v = ((const float4*)(x + row * 256))[l];
    float s = v.x + v.y + v.z + v.w;
    float q = v.x * v.x + v.y * v.y + v.z * v.z + v.w * v.w;
#pragma unroll
    for (int o = 32; o > 0; o >>= 1) {
        s += __shfl_xor(s, o, 64);
        q += __shfl_xor(q, o, 64);
    }
    const float mu = s * (1.0f / 256.0f);
    const float var = q * (1.0f / 256.0f) - mu * mu;
    const float rs = rsqrtf(var + 1e-5f);
    const float4 gg = ((const float4*)g)[l];
    ushort4 o4;
    o4.x = f2bf((v.x - mu) * rs * (gg.x + 1.0f));
    o4.y = f2bf((v.y - mu) * rs * (gg.y + 1.0f));
    o4.z = f2bf((v.z - mu) * rs * (gg.z + 1.0f));
    o4.w = f2bf((v.w - mu) * rs * (gg.w + 1.0f));
    ((ushort4*)(xn + row * 256))[l] = o4;
}

__global__ void __launch_bounds__(256) cast_bf16_kernel(const float* __restrict__ src,
                                                        u16* __restrict__ dst, float scale)
{
    const size_t i = (size_t)blockIdx.x * 256 + threadIdx.x;
    const float4 v = ((const float4*)src)[i];
    ushort4 o4;
    o4.x = f2bf(v.x * scale);
    o4.y = f2bf(v.y * scale);
    o4.z = f2bf(v.z * scale);
    o4.w = f2bf(v.w * scale);
    ((ushort4*)dst)[i] = o4;
}

extern "C" void kernel_launch(void* const* d_in, const int* in_sizes, int n_in,
                              void* d_out, int out_size, void* d_ws, size_t ws_size,
                              hipStream_t stream)
{
    (void)in_sizes; (void)n_in; (void)ws_size;
    const float* x     = (const float*)d_in[0];
    const float* gamma = (const float*)d_in[1];
    const float* Wq    = (const float*)d_in[2];
    const float* Wk    = (const float*)d_in[3];
    const float* Wv    = (const float*)d_in[4];
    const float* Wo    = (const float*)d_in[5];
    float* out = (float*)d_out;

    char* ws = (char*)d_ws;
    const size_t MB = 1048576;
    u16* wqt   = (u16*)(ws);             // [3][8][256][2048] bf16 (SCALE folded in Wq)
    u16* wkt   = (u16*)(ws + 8 * MB);
    u16* wvt   = (u16*)(ws + 16 * MB);
    u16* wo    = (u16*)(ws + 24 * MB);   // [256][16384] bf16
    u16* xn    = (u16*)(ws + 32 * MB);   // [4096][256] bf16
    u16* Mt    = (u16*)(ws + 34 * MB);   // [8*256][256] bf16 (Mt_h = M_h^T)
    u16* Nb    = (u16*)(ws + 35 * MB);   // [8*256][256] bf16 (contiguous after Mt)
    float* MtF = (float*)(ws + 36 * MB); // fp32 split-K accum: Mt (2 MB) + Nb (2 MB)
    float* NbF = (float*)(ws + 38 * MB);
    u16* Y     = (u16*)(ws + 44 * MB);   // [4096][2048] bf16
    u16* Zt    = (u16*)(ws + 60 * MB);   // [2][2048][2048] bf16

    hipMemsetAsync(d_out, 0, (size_t)out_size * sizeof(float), stream);
    hipMemsetAsync(MtF, 0, 4 * MB, stream);

    tcast3_kernel<<<dim3(32, 4, 24), 256, 0, stream>>>(Wq, Wk, Wv, wqt);
    cast_bf16_kernel<<<4096, 256, 0, stream>>>(Wo, wo, 1.0f);
    ln_kernel<<<4096, 64, 0, stream>>>(x, gamma, xn);

    // Mt_h[a,c] = sum_e wkt_h[a,e]*wqt_h[c,e] : split-K x4 (K-chunk 512), fp32 atomic
    gemm_bt<float, true><<<dim3(2, 2, 32), 256, 0, stream>>>(
        wkt, wqt, MtF, 512, 2048, 2048, 256,
        524288L, 0, 524288L, 0, 65536L, 0, 8, 1, 512L, 512L);

    // N_h[d',a] = sum_e Wo[d',h*2048+e]*wvt_h[a,e] : split-K x4, fp32 atomic
    gemm_bt<float, true><<<dim3(2, 2, 32), 256, 0, stream>>>(
        wo, wvt, NbF, 512, 16384, 2048, 256,
        2048L, 0, 524288L, 0, 65536L, 0, 8, 1, 512L, 512L);

    // cast MtF+NbF (4 MB contiguous) -> Mt+Nb (2 MB contiguous)
    cast_bf16_kernel<<<1024, 256, 0, stream>>>(MtF, Mt, 1.0f);

    // Y[t, h*256+a] = sum_c xn[t,c] * Mt[h*256+a, c]
    gemm_bt<u16, false><<<dim3(16, 32, 1), 256, 0, stream>>>(
        xn, Mt, Y, 256, 256, 256, 2048,
        0, 0, 0, 0, 0, 0, 1, 1, 0, 0);

    // Zt[b][h*256+d', j] = sum_a Nb[h*256+d', a] * xn[b*2048+j, a]
    gemm_bt<u16, false><<<dim3(16, 16, 2), 256, 0, stream>>>(
        Nb, xn, Zt, 256, 256, 256, 2048,
        0, 0, 0, 524288L, 0, 4194304L, 1, 2, 0, 0);

    // fused S -> softmax -> PV -> head-sum
    attn_fused<<<dim3(32, 16), 256, 0, stream>>>(Y, xn, Zt, out);
}